// Round 1
// baseline (203.853 us; speedup 1.0000x reference)
//
#include <hip/hip_runtime.h>

typedef float f32x4 __attribute__((ext_vector_type(4)));

// ---------------------------------------------------------------------------
// Kernel A: contract TT cores into dense Wd (1024x64) and Wu (64x1024).
//   Wd[i][j] = sum_{a,b} d1[0,i1,j1,a] d2[a,i2,j2,b] d3[b,i3,j3,0]
//     i = (i1,i2,i3) over (8,16,8)  -> i = i1*128 + i2*8 + i3
//     j = (j1,j2,j3) over (4,4,4)   -> j = j1*16 + j2*4 + j3
//   Wu[k][d] = sum_{a,b} u1[0,k1,o1,a] u2[a,k2,o2,b] u3[b,k3,o3,0]
//     k over (4,4,4), d over (8,16,8)
// ---------------------------------------------------------------------------
__global__ __launch_bounds__(256) void tt_build_w_kernel(
    const float* __restrict__ d1, const float* __restrict__ d2, const float* __restrict__ d3,
    const float* __restrict__ u1, const float* __restrict__ u2, const float* __restrict__ u3,
    float* __restrict__ Wd, float* __restrict__ Wu)
{
    int t = blockIdx.x * 256 + threadIdx.x;
    if (t < 65536) {
        int i = t >> 6, j = t & 63;
        int i1 = i >> 7, i2 = (i >> 3) & 15, i3 = i & 7;
        int j1 = j >> 4, j2 = (j >> 2) & 3, j3 = j & 3;
        float t3[8];
#pragma unroll
        for (int b = 0; b < 8; ++b) t3[b] = d3[(b * 8 + i3) * 4 + j3];
        float wsum = 0.f;
#pragma unroll
        for (int a = 0; a < 8; ++a) {
            float va = d1[(i1 * 4 + j1) * 8 + a];
            const float* p2 = d2 + ((a * 16 + i2) * 4 + j2) * 8;
            float wa = 0.f;
#pragma unroll
            for (int b = 0; b < 8; ++b) wa = fmaf(p2[b], t3[b], wa);
            wsum = fmaf(va, wa, wsum);
        }
        Wd[i * 64 + j] = wsum;
    } else {
        int t2 = t - 65536;
        int k = t2 >> 10, d = t2 & 1023;
        int k1 = k >> 4, k2 = (k >> 2) & 3, k3 = k & 3;
        int o1 = d >> 7, o2 = (d >> 3) & 15, o3 = d & 7;
        float t3[8];
#pragma unroll
        for (int b = 0; b < 8; ++b) t3[b] = u3[(b * 4 + k3) * 8 + o3];
        float wsum = 0.f;
#pragma unroll
        for (int a = 0; a < 8; ++a) {
            float va = u1[(k1 * 8 + o1) * 8 + a];
            const float* p2 = u2 + ((a * 4 + k2) * 16 + o2) * 8;
            float wa = 0.f;
#pragma unroll
            for (int b = 0; b < 8; ++b) wa = fmaf(p2[b], t3[b], wa);
            wsum = fmaf(va, wa, wsum);
        }
        Wu[k * 1024 + d] = wsum;
    }
}

// ---------------------------------------------------------------------------
// Kernel B: y = relu(x @ Wd + bd) @ Wu + bu, 32 rows per block.
// Phase 1: wave w covers k in [w*256, w*256+256), lane = z-column (64 cols).
//          x reads are wave-uniform (scalarizable), Wd reads coalesced.
// Phase 2: wave w covers rows [w*8, w*8+8), two col-half passes of 512 cols.
// ---------------------------------------------------------------------------
__global__ __launch_bounds__(256) void tt_main_kernel(
    const float* __restrict__ x, const float* __restrict__ Wd, const float* __restrict__ Wu,
    const float* __restrict__ bd, const float* __restrict__ bu, float* __restrict__ y)
{
    __shared__ float red[4][32][64];
    __shared__ float zs[32][64];
    const int t = threadIdx.x;
    const int lane = t & 63;
    const int w = __builtin_amdgcn_readfirstlane(t >> 6);
    const int rowbase = blockIdx.x * 32;
    const int kbase = w * 256;
    const float* xq = x + (size_t)rowbase * 1024 + kbase;

    // ---------------- phase 1: z_partial = x @ Wd (per-wave k-quarter) -----
    float acc[32];
#pragma unroll
    for (int r = 0; r < 32; ++r) acc[r] = 0.f;

    for (int k4 = 0; k4 < 256; k4 += 4) {
        float wvv[4];
#pragma unroll
        for (int kk = 0; kk < 4; ++kk) wvv[kk] = Wd[(kbase + k4 + kk) * 64 + lane];
#pragma unroll
        for (int h = 0; h < 2; ++h) {
            f32x4 xv[16];
#pragma unroll
            for (int r = 0; r < 16; ++r)
                xv[r] = *reinterpret_cast<const f32x4*>(xq + (h * 16 + r) * 1024 + k4);
#pragma unroll
            for (int kk = 0; kk < 4; ++kk) {
#pragma unroll
                for (int r = 0; r < 16; ++r)
                    acc[h * 16 + r] = fmaf(xv[r][kk], wvv[kk], acc[h * 16 + r]);
            }
        }
    }
#pragma unroll
    for (int r = 0; r < 32; ++r) red[w][r][lane] = acc[r];
    __syncthreads();

    // ---------------- cross-wave reduce + bias + relu ----------------------
#pragma unroll
    for (int i = 0; i < 8; ++i) {
        int idx = t + i * 256;
        int r = idx >> 6, j = idx & 63;
        float s = red[0][r][j] + red[1][r][j] + red[2][r][j] + red[3][r][j] + bd[j];
        zs[r][j] = s > 0.f ? s : 0.f;
    }
    __syncthreads();

    // ---------------- phase 2: y = z @ Wu + bu -----------------------------
    const int r0 = w * 8;
#pragma unroll
    for (int ch = 0; ch < 2; ++ch) {
        const int cb = ch * 512 + lane * 4;
        f32x4 a0[8], a1[8];
#pragma unroll
        for (int r = 0; r < 8; ++r) {
#pragma unroll
            for (int e = 0; e < 4; ++e) { a0[r][e] = 0.f; a1[r][e] = 0.f; }
        }
        for (int k4 = 0; k4 < 64; k4 += 4) {
            f32x4 zv[8];
#pragma unroll
            for (int r = 0; r < 8; ++r)
                zv[r] = *reinterpret_cast<const f32x4*>(&zs[r0 + r][k4]);
#pragma unroll
            for (int kk = 0; kk < 4; ++kk) {
                const f32x4 wu0 = *reinterpret_cast<const f32x4*>(&Wu[(k4 + kk) * 1024 + cb]);
                const f32x4 wu1 = *reinterpret_cast<const f32x4*>(&Wu[(k4 + kk) * 1024 + cb + 256]);
#pragma unroll
                for (int r = 0; r < 8; ++r) {
                    float zk = zv[r][kk];
#pragma unroll
                    for (int e = 0; e < 4; ++e) {
                        a0[r][e] = fmaf(zk, wu0[e], a0[r][e]);
                        a1[r][e] = fmaf(zk, wu1[e], a1[r][e]);
                    }
                }
            }
        }
        const f32x4 b0 = *reinterpret_cast<const f32x4*>(&bu[cb]);
        const f32x4 b1 = *reinterpret_cast<const f32x4*>(&bu[cb + 256]);
#pragma unroll
        for (int r = 0; r < 8; ++r) {
            f32x4 o0, o1;
#pragma unroll
            for (int e = 0; e < 4; ++e) { o0[e] = a0[r][e] + b0[e]; o1[e] = a1[r][e] + b1[e]; }
            *reinterpret_cast<f32x4*>(&y[(size_t)(rowbase + r0 + r) * 1024 + cb]) = o0;
            *reinterpret_cast<f32x4*>(&y[(size_t)(rowbase + r0 + r) * 1024 + cb + 256]) = o1;
        }
    }
}

extern "C" void kernel_launch(void* const* d_in, const int* in_sizes, int n_in,
                              void* d_out, int out_size, void* d_ws, size_t ws_size,
                              hipStream_t stream) {
    const float* x  = (const float*)d_in[0];
    const float* d1 = (const float*)d_in[1];
    const float* d2 = (const float*)d_in[2];
    const float* d3 = (const float*)d_in[3];
    const float* u1 = (const float*)d_in[4];
    const float* u2 = (const float*)d_in[5];
    const float* u3 = (const float*)d_in[6];
    const float* bd = (const float*)d_in[7];
    const float* bu = (const float*)d_in[8];
    float* y  = (float*)d_out;
    float* Wd = (float*)d_ws;          // 1024*64 floats
    float* Wu = Wd + 65536;            // 64*1024 floats

    hipLaunchKernelGGL(tt_build_w_kernel, dim3(512), dim3(256), 0, stream,
                       d1, d2, d3, u1, u2, u3, Wd, Wu);
    hipLaunchKernelGGL(tt_main_kernel, dim3(512), dim3(256), 0, stream,
                       x, Wd, Wu, bd, bu, y);
}

// Round 2
// 52.439 us; speedup vs baseline: 3.8874x; 3.8874x over previous
//
#include <hip/hip_runtime.h>

typedef float f32x4 __attribute__((ext_vector_type(4)));
typedef short short8 __attribute__((ext_vector_type(8)));  // 8 x bf16 bits

static __device__ __forceinline__ unsigned short f2bf(float f) {
    __bf16 h = (__bf16)f;
    return __builtin_bit_cast(unsigned short, h);
}

// ---------------------------------------------------------------------------
// Kernel A: contract TT cores into dense TRANSPOSED bf16 weights.
//   WdT[j][i] = Wd[i][j],  j in [0,64)  (z-col), i in [0,1024) (x-dim)
//   WuT[d][k] = Wu[k][d],  d in [0,1024) (y-col), k in [0,64)  (z-dim)
// Consecutive threads write consecutive elements of the transposed layout.
// ---------------------------------------------------------------------------
__global__ __launch_bounds__(256) void tt_build_w_kernel(
    const float* __restrict__ d1, const float* __restrict__ d2, const float* __restrict__ d3,
    const float* __restrict__ u1, const float* __restrict__ u2, const float* __restrict__ u3,
    unsigned short* __restrict__ WdT, unsigned short* __restrict__ WuT)
{
    int t = blockIdx.x * 256 + threadIdx.x;
    if (t < 65536) {
        int j = t >> 10, i = t & 1023;          // consecutive i -> coalesced WdT row
        int i1 = i >> 7, i2 = (i >> 3) & 15, i3 = i & 7;
        int j1 = j >> 4, j2 = (j >> 2) & 3, j3 = j & 3;
        float t3[8];
#pragma unroll
        for (int b = 0; b < 8; ++b) t3[b] = d3[(b * 8 + i3) * 4 + j3];
        float wsum = 0.f;
#pragma unroll
        for (int a = 0; a < 8; ++a) {
            float va = d1[(i1 * 4 + j1) * 8 + a];
            const float* p2 = d2 + ((a * 16 + i2) * 4 + j2) * 8;
            float wa = 0.f;
#pragma unroll
            for (int b = 0; b < 8; ++b) wa = fmaf(p2[b], t3[b], wa);
            wsum = fmaf(va, wa, wsum);
        }
        WdT[j * 1024 + i] = f2bf(wsum);
    } else {
        int t2 = t - 65536;
        int d = t2 >> 6, k = t2 & 63;           // consecutive k -> coalesced WuT row
        int k1 = k >> 4, k2 = (k >> 2) & 3, k3 = k & 3;
        int o1 = d >> 7, o2 = (d >> 3) & 15, o3 = d & 7;
        float t3[8];
#pragma unroll
        for (int b = 0; b < 8; ++b) t3[b] = u3[(b * 4 + k3) * 8 + o3];
        float wsum = 0.f;
#pragma unroll
        for (int a = 0; a < 8; ++a) {
            float va = u1[(k1 * 8 + o1) * 8 + a];
            const float* p2 = u2 + ((a * 4 + k2) * 16 + o2) * 8;
            float wa = 0.f;
#pragma unroll
            for (int b = 0; b < 8; ++b) wa = fmaf(p2[b], t3[b], wa);
            wsum = fmaf(va, wa, wsum);
        }
        WuT[d * 64 + k] = f2bf(wsum);
    }
}

// ---------------------------------------------------------------------------
// Main kernel: y = relu(x @ Wd + bd) @ Wu + bu via bf16 MFMA (16x16x32).
// Block = 16 rows, 4 waves. Phase 1: wave w owns k-quarter [256w,256w+256);
// cross-wave LDS reduce + bias + relu -> bf16 zlds. Phase 2: wave w owns
// y-cols [256w, 256w+256) as 16 col-tiles x 2 mfma (K=64).
// Fragment layouts (guide-verified): A/B lane holds 8 contiguous k at
// row/col = lane&15, kbase = (lane>>4)*8. C/D: col=lane&15, row=(lane>>4)*4+reg.
// ---------------------------------------------------------------------------
__global__ __launch_bounds__(256) void tt_main_kernel(
    const float* __restrict__ x, const unsigned short* __restrict__ WdT,
    const unsigned short* __restrict__ WuT, const float* __restrict__ bd,
    const float* __restrict__ bu, float* __restrict__ y)
{
    __shared__ float red[4][1024];
    __shared__ unsigned short zlds[16 * 80];   // [row][80] bf16, stride 80 for b128 align
    const int t = threadIdx.x;
    const int lane = t & 63;
    const int w = t >> 6;
    const int row16 = lane & 15;   // A row / B col / D col
    const int kg = lane >> 4;      // k-group (8 elems each)
    const int rb = blockIdx.x * 16;

    // ---------------- phase 1: z partial = x @ Wd over wave's k-quarter ----
    f32x4 acc[4] = {{0.f, 0.f, 0.f, 0.f}, {0.f, 0.f, 0.f, 0.f},
                    {0.f, 0.f, 0.f, 0.f}, {0.f, 0.f, 0.f, 0.f}};
    const int kb = w * 256;
    const float* xp = x + (size_t)(rb + row16) * 1024 + kb + kg * 8;
#pragma unroll
    for (int ks = 0; ks < 8; ++ks) {
        f32x4 x0 = *reinterpret_cast<const f32x4*>(xp);
        f32x4 x1 = *reinterpret_cast<const f32x4*>(xp + 4);
        xp += 32;
        union { short8 v; unsigned short e[8]; } a;
        a.e[0] = f2bf(x0[0]); a.e[1] = f2bf(x0[1]); a.e[2] = f2bf(x0[2]); a.e[3] = f2bf(x0[3]);
        a.e[4] = f2bf(x1[0]); a.e[5] = f2bf(x1[1]); a.e[6] = f2bf(x1[2]); a.e[7] = f2bf(x1[3]);
#pragma unroll
        for (int ct = 0; ct < 4; ++ct) {
            short8 b = *reinterpret_cast<const short8*>(
                WdT + (ct * 16 + row16) * 1024 + kb + ks * 32 + kg * 8);
            acc[ct] = __builtin_amdgcn_mfma_f32_16x16x32_bf16(a.v, b, acc[ct], 0, 0, 0);
        }
    }
#pragma unroll
    for (int ct = 0; ct < 4; ++ct)
        *reinterpret_cast<f32x4*>(&red[w][ct * 256 + lane * 4]) = acc[ct];
    __syncthreads();

    // ---------------- cross-wave reduce + bias + relu -> bf16 zlds ---------
    {
        // thread t handles elems e = t*4 + r: ct = t>>6, lane2 = t&63
        f32x4 v0 = *reinterpret_cast<const f32x4*>(&red[0][t * 4]);
        f32x4 v1 = *reinterpret_cast<const f32x4*>(&red[1][t * 4]);
        f32x4 v2 = *reinterpret_cast<const f32x4*>(&red[2][t * 4]);
        f32x4 v3 = *reinterpret_cast<const f32x4*>(&red[3][t * 4]);
        int ct = t >> 6, lane2 = t & 63;
        int colz = ct * 16 + (lane2 & 15);
        int rowz = (lane2 >> 4) * 4;
        float bdv = bd[colz];
#pragma unroll
        for (int r = 0; r < 4; ++r) {
            float zz = v0[r] + v1[r] + v2[r] + v3[r] + bdv;
            zz = zz > 0.f ? zz : 0.f;
            zlds[(rowz + r) * 80 + colz] = f2bf(zz);
        }
    }
    __syncthreads();

    // ---------------- phase 2: y = z @ Wu + bu -----------------------------
    short8 az0 = *reinterpret_cast<const short8*>(zlds + row16 * 80 + kg * 8);
    short8 az1 = *reinterpret_cast<const short8*>(zlds + row16 * 80 + 32 + kg * 8);
    const int rowy = rb + kg * 4;   // D rows: + reg
#pragma unroll
    for (int ct = 0; ct < 16; ++ct) {
        int col = (w * 16 + ct) * 16 + row16;
        short8 b0 = *reinterpret_cast<const short8*>(WuT + col * 64 + kg * 8);
        short8 b1 = *reinterpret_cast<const short8*>(WuT + col * 64 + 32 + kg * 8);
        f32x4 a2 = {0.f, 0.f, 0.f, 0.f};
        a2 = __builtin_amdgcn_mfma_f32_16x16x32_bf16(az0, b0, a2, 0, 0, 0);
        a2 = __builtin_amdgcn_mfma_f32_16x16x32_bf16(az1, b1, a2, 0, 0, 0);
        float buv = bu[col];
#pragma unroll
        for (int r = 0; r < 4; ++r)
            y[(size_t)(rowy + r) * 1024 + col] = a2[r] + buv;
    }
}

extern "C" void kernel_launch(void* const* d_in, const int* in_sizes, int n_in,
                              void* d_out, int out_size, void* d_ws, size_t ws_size,
                              hipStream_t stream) {
    const float* x  = (const float*)d_in[0];
    const float* d1 = (const float*)d_in[1];
    const float* d2 = (const float*)d_in[2];
    const float* d3 = (const float*)d_in[3];
    const float* u1 = (const float*)d_in[4];
    const float* u2 = (const float*)d_in[5];
    const float* u3 = (const float*)d_in[6];
    const float* bd = (const float*)d_in[7];
    const float* bu = (const float*)d_in[8];
    float* y = (float*)d_out;
    unsigned short* WdT = (unsigned short*)d_ws;   // 64x1024 bf16
    unsigned short* WuT = WdT + 65536;             // 1024x64 bf16

    hipLaunchKernelGGL(tt_build_w_kernel, dim3(512), dim3(256), 0, stream,
                       d1, d2, d3, u1, u2, u3, WdT, WuT);
    hipLaunchKernelGGL(tt_main_kernel, dim3(1024), dim3(256), 0, stream,
                       x, WdT, WuT, bd, bu, y);
}